// Round 8
// baseline (116.515 us; speedup 1.0000x reference)
//
#include <hip/hip_runtime.h>

// ---------------------------------------------------------------------------
// LocalCausalSelfAttention: x@Wqkv+b -> RoPE(q,k) -> windowed causal attn
// -> @Wproj+b.  B=2 T=2048 C=1024 H=16 Dh=64 W=128.
// External I/O: fp32. Internal: bf16 MFMA compute.
// RoPE fused into GEMM1 epilogue. GEMMs use 3-deep counted-vmcnt pipeline.
// ---------------------------------------------------------------------------

using bf16x8 = short  __attribute__((ext_vector_type(8)));
using f32x4  = float __attribute__((ext_vector_type(4)));

__device__ __forceinline__ float bf2f(unsigned short u) {
    return __uint_as_float(((unsigned int)u) << 16);
}
__device__ __forceinline__ unsigned short f2bf(float f) {
    unsigned int u = __float_as_uint(f);
    u += 0x7fffu + ((u >> 16) & 1u);      // RNE
    return (unsigned short)(u >> 16);
}

// async global->LDS, 16B per lane; LDS dest = uniform base + lane*16 (m97/m104)
__device__ __forceinline__ void gload_lds16(const unsigned short* g,
                                            unsigned short* l) {
    __builtin_amdgcn_global_load_lds(
        (const __attribute__((address_space(1))) unsigned int*)(g),
        (__attribute__((address_space(3))) unsigned int*)(l),
        16, 0, 0);
}

// counted vmcnt wait (immediate must be a literal -> constexpr dispatch)
template <int N>
__device__ __forceinline__ void vm_wait() {
    static_assert(N == 0 || N == 3 || N == 4 || N == 6 || N == 8, "add case");
    if constexpr (N == 0)      asm volatile("s_waitcnt vmcnt(0)" ::: "memory");
    else if constexpr (N == 3) asm volatile("s_waitcnt vmcnt(3)" ::: "memory");
    else if constexpr (N == 4) asm volatile("s_waitcnt vmcnt(4)" ::: "memory");
    else if constexpr (N == 6) asm volatile("s_waitcnt vmcnt(6)" ::: "memory");
    else                       asm volatile("s_waitcnt vmcnt(8)" ::: "memory");
}
__device__ __forceinline__ void lgkm_wait0() {
    asm volatile("s_waitcnt lgkmcnt(0)" ::: "memory");
}

// ---------------- fp32 -> bf16 elementwise (vectorized) ---------------------
__global__ __launch_bounds__(256) void f32_to_bf16_kernel(
        const float* __restrict__ in, unsigned short* __restrict__ out, int n4) {
    int i = blockIdx.x * 256 + threadIdx.x;
    int stride = gridDim.x * 256;
    for (; i < n4; i += stride) {
        float4 v = ((const float4*)in)[i];
        ushort4 o;
        o.x = f2bf(v.x); o.y = f2bf(v.y); o.z = f2bf(v.z); o.w = f2bf(v.w);
        ((ushort4*)out)[i] = o;
    }
}

// ---------------- transpose + downcast (fp32 KxN -> bf16 NxK) ---------------
__global__ __launch_bounds__(256) void transpose_f32_bf16(
        const float* __restrict__ W, unsigned short* __restrict__ WT,
        int rows, int cols) {
    __shared__ unsigned short tile[32][33];
    int c0 = blockIdx.x * 32, r0 = blockIdx.y * 32;
    int tx = threadIdx.x, ty = threadIdx.y;
    for (int i = ty; i < 32; i += 8)
        tile[i][tx] = f2bf(W[(size_t)(r0 + i) * cols + c0 + tx]);
    __syncthreads();
    for (int i = ty; i < 32; i += 8)
        WT[(size_t)(c0 + i) * rows + r0 + tx] = tile[tx][i];
}

// ---------------- GEMM: C[M,N] = A[M,K] @ Bt[N,K]^T + bias ------------------
// m97 LDS layout + 3-deep counted-vmcnt pipeline (T3/T4): 3 LDS buffers,
// stage tile t+3 while tiles t+1,t+2 stay in flight; raw s_barrier (no
// implicit drain); main loop never waits vmcnt(0).
// Optional fused RoPE epilogue (GEMM1). Wave grid (BM/WM)x(BN/WN) == 4.
template <int BM, int BN, int WM, int WN, bool OUT_BF16, bool FUSE_ROPE>
__global__ __launch_bounds__(256) void gemm_lds(
        const unsigned short* __restrict__ A,
        const unsigned short* __restrict__ Bt,
        const float* __restrict__ bias,
        void* __restrict__ Cv,
        const float* __restrict__ tab,
        int M, int N, int K) {
    constexpr int MI = BM / 16;       // A staging instrs per K-step
    constexpr int NI = BN / 16;       // B staging instrs per K-step
    constexpr int PW = (MI + NI) / 4; // per wave
    constexpr int WGN = BN / WN;
    constexpr int MR = WM / 16, NR = WN / 16;

    __shared__ unsigned short As[3][BM * 32];
    __shared__ unsigned short Bs[3][BN * 32];

    int row0 = blockIdx.y * BM, col0 = blockIdx.x * BN;
    int tid = threadIdx.x;
    int lane = tid & 63, wid = tid >> 6;
    int wr = wid / WGN, wc = wid % WGN;
    int fr = lane & 15, kq = lane >> 4;
    int r_in = lane >> 2, cg8 = (lane & 3) * 8;   // staging: 16 rows x 4 chunks

    f32x4 acc[MR][NR];
    #pragma unroll
    for (int i = 0; i < MR; ++i)
        #pragma unroll
        for (int j = 0; j < NR; ++j)
            acc[i][j] = (f32x4){0.f, 0.f, 0.f, 0.f};

    auto stage = [&](int buf, int kt) {
        #pragma unroll
        for (int t = 0; t < PW; ++t) {
            int j = wid * PW + t;                  // wave-uniform
            if (j < MI) {
                int row = j * 16 + r_in;
                gload_lds16(A + (size_t)(row0 + row) * K + kt + cg8,
                            &As[buf][j * 512]);
            } else {
                int jb = j - MI;
                int row = jb * 16 + r_in;
                gload_lds16(Bt + (size_t)(col0 + row) * K + kt + cg8,
                            &Bs[buf][jb * 512]);
            }
        }
    };
    auto compute = [&](int buf) {
        bf16x8 af[MR], bfv[NR];
        #pragma unroll
        for (int i = 0; i < MR; ++i)
            af[i] = *(const bf16x8*)&As[buf][(wr * WM + i * 16 + fr) * 32 + kq * 8];
        #pragma unroll
        for (int j = 0; j < NR; ++j)
            bfv[j] = *(const bf16x8*)&Bs[buf][(wc * WN + j * 16 + fr) * 32 + kq * 8];
        #pragma unroll
        for (int i = 0; i < MR; ++i)
            #pragma unroll
            for (int j = 0; j < NR; ++j)
                acc[i][j] = __builtin_amdgcn_mfma_f32_16x16x32_bf16(
                                af[i], bfv[j], acc[i][j], 0, 0, 0);
    };

    int nt = K >> 5;                               // K-steps (K % 32 == 0, >=4)
    stage(0, 0);
    stage(1, 32);
    stage(2, 64);
    int t = 0;
    for (; t < nt - 3; ++t) {
        vm_wait<2 * PW>();                         // my tile-t loads landed
        __builtin_amdgcn_s_barrier();              // everyone's landed
        compute(t % 3);
        lgkm_wait0();                              // my ds_reads serviced
        __builtin_amdgcn_s_barrier();              // all done reading buf t%3
        stage(t % 3, (t + 3) * 32);                // overwrite safely (async)
    }
    vm_wait<2 * PW>(); __builtin_amdgcn_s_barrier(); compute(t % 3); ++t;
    vm_wait<PW>();     __builtin_amdgcn_s_barrier(); compute(t % 3); ++t;
    vm_wait<0>();      __builtin_amdgcn_s_barrier(); compute(t % 3);

    int rg = kq * 4;
    #pragma unroll
    for (int j = 0; j < NR; ++j) {
        int col = col0 + wc * WN + j * 16 + fr;
        float bz = bias[col];
        #pragma unroll
        for (int i = 0; i < MR; ++i) {
            float v4[4];
            #pragma unroll
            for (int r = 0; r < 4; ++r) v4[r] = acc[i][j][r] + bz;
            if constexpr (FUSE_ROPE) {
                if (col0 < 2048) {                 // q,k cols: apply RoPE
                    int ii = (j * 16 + fr) >> 1;   // rotary pair idx (head-rel)
                    bool odd = fr & 1;
                    #pragma unroll
                    for (int r = 0; r < 4; ++r) {
                        float part = __shfl_xor(v4[r], 1);
                        int trow = (row0 + wr * WM + i * 16 + rg + r) & 2047;
                        float c = tab[(trow * 32 + ii) * 2];
                        float s = tab[(trow * 32 + ii) * 2 + 1];
                        v4[r] = odd ? fmaf(v4[r], c,  part * s)
                                    : fmaf(v4[r], c, -part * s);
                    }
                }
            }
            #pragma unroll
            for (int r = 0; r < 4; ++r) {
                int row = row0 + wr * WM + i * 16 + rg + r;
                if constexpr (OUT_BF16)
                    ((unsigned short*)Cv)[(size_t)row * N + col] = f2bf(v4[r]);
                else
                    ((float*)Cv)[(size_t)row * N + col] = v4[r];
            }
        }
    }
}

// ---------------- RoPE table ------------------------------------------------
__global__ __launch_bounds__(256) void rope_table_kernel(float* __restrict__ tab) {
    int idx = blockIdx.x * 256 + threadIdx.x;   // 65536 = 2048*32
    int t = idx >> 5, i = idx & 31;
    float inv = powf(10000.0f, -(float)i / 32.0f);
    float ang = (float)t * inv;
    tab[idx * 2]     = cosf(ang);
    tab[idx * 2 + 1] = sinf(ang);
}

// ---------------- MFMA windowed causal attention ----------------------------
// Block = (b, h, 64-query tile), 4 waves, wave owns 16 queries.
#define VTS 200   // Vt col stride (keys): mult of 8 (16B align), 2-way banks
#define PSS 168   // P row stride: mult of 8, 2-way banks, >= 160

__global__ __launch_bounds__(256) void attn_kernel(
        const unsigned short* __restrict__ qkv, unsigned short* __restrict__ aout) {
    __shared__ unsigned short Vt[64 * VTS];        // 25600 B
    __shared__ unsigned short Ps[4 * 16 * PSS];    // 21504 B

    int bid = blockIdx.x;
    int h  = bid & 15;
    int qt = (bid >> 4) & 31;
    int b  = bid >> 9;
    int Q0 = qt * 64;
    int kbase = Q0 - 127; if (kbase < 0) kbase = 0;
    int nk = Q0 + 64 - kbase;                       // 64..191 valid keys
    int tid = threadIdx.x;

    // ---- stage V transposed: Vt[dim][key], zero keys in [nk, VTS) ----
    {
        int r32 = tid & 31;
        int c8  = (tid >> 5) * 8;
        #pragma unroll
        for (int p = 0; p < 7; ++p) {
            int r = p * 32 + r32;
            if (r < VTS) {
                unsigned int wv[4] = {0u, 0u, 0u, 0u};
                if (r < nk) {
                    uint4 v = *(const uint4*)(qkv +
                        (size_t)(b * 2048 + kbase + r) * 3072 + 2048 + h * 64 + c8);
                    wv[0] = v.x; wv[1] = v.y; wv[2] = v.z; wv[3] = v.w;
                }
                #pragma unroll
                for (int j = 0; j < 4; ++j) {
                    Vt[(c8 + 2 * j)     * VTS + r] = (unsigned short)(wv[j] & 0xffffu);
                    Vt[(c8 + 2 * j + 1) * VTS + r] = (unsigned short)(wv[j] >> 16);
                }
            }
        }
    }
    __syncthreads();

    int lane = tid & 63, w = tid >> 6;
    int qw0 = Q0 + w * 16;
    int lo = lane & 15, hi = lane >> 4;

    // ---- Q fragments (direct global) ----
    const unsigned short* qg =
        qkv + (size_t)(b * 2048 + qw0 + lo) * 3072 + h * 64 + hi * 8;
    bf16x8 aq0 = *(const bf16x8*)qg;
    bf16x8 aq1 = *(const bf16x8*)(qg + 32);

    // ---- key-tile range for this wave (even # of tiles when possible) ----
    int klo = qw0 - 127; if (klo < kbase) klo = kbase;
    int t0 = (klo - kbase) >> 4;
    int t1 = (qw0 + 15 - kbase) >> 4;
    int ntiles = t1 - t0 + 1;
    if ((ntiles & 1) && t0 > 0) { --t0; ++ntiles; }  // extra tile fully masked
    int nks = (ntiles + 1) >> 1;
    int wkb = t0 * 16;

    // ---- QK^T: S tiles (K frags direct from global) ----
    f32x4 s[10];
    #pragma unroll
    for (int i = 0; i < 10; ++i) s[i] = (f32x4){0.f, 0.f, 0.f, 0.f};
    #pragma unroll
    for (int i = 0; i < 10; ++i) {
        if (i < ntiles) {
            const unsigned short* kg = qkv +
                (size_t)(b * 2048 + kbase + (t0 + i) * 16 + lo) * 3072
                + 1024 + h * 64 + hi * 8;
            bf16x8 bk0 = *(const bf16x8*)kg;
            bf16x8 bk1 = *(const bf16x8*)(kg + 32);
            s[i] = __builtin_amdgcn_mfma_f32_16x16x32_bf16(aq0, bk0, s[i], 0, 0, 0);
            s[i] = __builtin_amdgcn_mfma_f32_16x16x32_bf16(aq1, bk1, s[i], 0, 0, 0);
        }
    }

    // ---- mask + softmax (rows = hi*4+r, cols = key) ----
    const float scale = 0.125f;                    // 1/sqrt(64)
    float mx[4] = {-1e30f, -1e30f, -1e30f, -1e30f};
    #pragma unroll
    for (int i = 0; i < 10; ++i) {
        if (i < ntiles) {
            int ka = kbase + (t0 + i) * 16 + lo;
            #pragma unroll
            for (int r = 0; r < 4; ++r) {
                int rel = (qw0 + hi * 4 + r) - ka;
                bool ok = (rel >= 0) && (rel < 128);
                float v = ok ? s[i][r] * scale : -1e30f;
                s[i][r] = v;
                mx[r] = fmaxf(mx[r], v);
            }
        }
    }
    #pragma unroll
    for (int r = 0; r < 4; ++r)
        #pragma unroll
        for (int o = 1; o < 16; o <<= 1)
            mx[r] = fmaxf(mx[r], __shfl_xor(mx[r], o));

    float sum[4] = {0.f, 0.f, 0.f, 0.f};
    #pragma unroll
    for (int i = 0; i < 10; ++i) {
        if (i < ntiles) {
            #pragma unroll
            for (int r = 0; r < 4; ++r) {
                float e = __expf(s[i][r] - mx[r]);
                s[i][r] = e;
                sum[r] += e;
            }
        }
    }
    #pragma unroll
    for (int r = 0; r < 4; ++r) {
        #pragma unroll
        for (int o = 1; o < 16; o <<= 1)
            sum[r] += __shfl_xor(sum[r], o);
        sum[r] = 1.0f / sum[r];
    }

    // ---- normalized P -> LDS (bf16) ----
    unsigned short* pw = &Ps[(w * 16) * PSS];
    #pragma unroll
    for (int i = 0; i < 10; ++i) {
        if (i < ntiles) {
            #pragma unroll
            for (int r = 0; r < 4; ++r)
                pw[(hi * 4 + r) * PSS + i * 16 + lo] = f2bf(s[i][r] * sum[r]);
        }
    }
    if (ntiles & 1) {                              // zero the pad stripe
        int zr = lane >> 2, zc = ntiles * 16 + (lane & 3) * 4;
        *(ushort4*)&pw[zr * PSS + zc] = (ushort4){0, 0, 0, 0};
    }

    // ---- PV: O[16q][64d] = P @ V ----
    f32x4 o[4];
    #pragma unroll
    for (int dt = 0; dt < 4; ++dt) o[dt] = (f32x4){0.f, 0.f, 0.f, 0.f};
    #pragma unroll
    for (int ks = 0; ks < 5; ++ks) {
        if (ks < nks) {
            bf16x8 pa = *(const bf16x8*)&Ps[(w * 16 + lo) * PSS + ks * 32 + hi * 8];
            #pragma unroll
            for (int dt = 0; dt < 4; ++dt) {
                bf16x8 vb = *(const bf16x8*)&Vt[(dt * 16 + lo) * VTS
                                                + wkb + ks * 32 + hi * 8];
                o[dt] = __builtin_amdgcn_mfma_f32_16x16x32_bf16(pa, vb, o[dt], 0, 0, 0);
            }
        }
    }

    // ---- store O (D-layout: col=dim=lo, row=hi*4+r) ----
    #pragma unroll
    for (int dt = 0; dt < 4; ++dt)
        #pragma unroll
        for (int r = 0; r < 4; ++r)
            aout[(size_t)(b * 2048 + qw0 + hi * 4 + r) * 1024
                 + h * 64 + dt * 16 + lo] = f2bf(o[dt][r]);
}

// ---------------------------------------------------------------------------
extern "C" void kernel_launch(void* const* d_in, const int* in_sizes, int n_in,
                              void* d_out, int out_size, void* d_ws, size_t ws_size,
                              hipStream_t stream) {
    const float* x     = (const float*)d_in[0];  // [2,2048,1024] fp32
    const float* Wqkv  = (const float*)d_in[1];  // [1024,3072]  fp32
    const float* bqkv  = (const float*)d_in[2];  // [3072]       fp32
    const float* Wproj = (const float*)d_in[3];  // [1024,1024]  fp32
    const float* bproj = (const float*)d_in[4];  // [1024]       fp32
    float* out = (float*)d_out;                  // [2,2048,1024] fp32

    char* ws = (char*)d_ws;
    unsigned short* WqkvT  = (unsigned short*)(ws);                // bf16 3072x1024:  6291456 B
    unsigned short* WprojT = (unsigned short*)(ws + 6291456);      // bf16 1024x1024:  2097152 B
    unsigned short* xb     = (unsigned short*)(ws + 8388608);      // bf16 4096x1024:  8388608 B
    unsigned short* qkv    = (unsigned short*)(ws + 16777216);     // bf16 4096x3072: 25165824 B
    float*          tab    = (float*)        (ws + 41943040);      // f32 2048x32x2:    524288 B
    unsigned short* attno  = (unsigned short*)(ws + 42467328);     // bf16 4096x1024:  8388608 B

    transpose_f32_bf16<<<dim3(96, 32), dim3(32, 8), 0, stream>>>(Wqkv,  WqkvT,  1024, 3072);
    transpose_f32_bf16<<<dim3(32, 32), dim3(32, 8), 0, stream>>>(Wproj, WprojT, 1024, 1024);
    f32_to_bf16_kernel<<<1024, 256, 0, stream>>>(x, xb, 4194304 / 4);
    rope_table_kernel<<<256, 256, 0, stream>>>(tab);

    // qkv = xb @ WqkvT^T + bqkv, RoPE fused in epilogue (bf16 out)
    gemm_lds<128, 128, 64, 64, true, true>
        <<<dim3(24, 32), 256, 0, stream>>>(xb, WqkvT, bqkv, qkv, tab, 4096, 3072, 1024);
    attn_kernel<<<1024, 256, 0, stream>>>(qkv, attno);
    // out = attno @ WprojT^T + bproj (fp32 out) 128x64 tile, 512 blocks
    gemm_lds<128, 64, 32, 64, false, false>
        <<<dim3(16, 32), 256, 0, stream>>>(attno, WprojT, bproj, out, nullptr, 4096, 1024, 1024);
}